// Round 9
// baseline (327.057 us; speedup 1.0000x reference)
//
#include <hip/hip_runtime.h>

// SNN forward: [GEMM1+scan1 fused, 128x128, dbuf K-loop, direct-global spike
// store] -> GEMM2 (split-K x2) -> scan2(sum halves).
// f16 split-2: W = hi + lo (both f16), residual ~2^-24 => fp32-grade MFMA.
// X and spikes are exact in f16.

#define NN 64
#define II 256
#define HH 1024
#define OO 18
#define TT 500

#define D_SR 0.9048374180359595f   // exp(-1/10)
#define C_SR 0.27182818284590454f  // e/10
#define D_RF 0.36787944117144233f  // exp(-1)
#define C_RF 2.718281828459045f    // e
#define THETA 10.0f
#define REFS (-20.0f)

typedef _Float16 f16;
typedef _Float16 f16x2 __attribute__((ext_vector_type(2)));
typedef _Float16 f16x8 __attribute__((ext_vector_type(8)));
typedef float f32x4 __attribute__((ext_vector_type(4)));

__device__ __forceinline__ void gl2lds16(const void* g, void* l) {
    __builtin_amdgcn_global_load_lds(
        (const __attribute__((address_space(1))) void*)g,
        (__attribute__((address_space(3))) void*)l, 16, 0, 0);
}

// ---------------- prep: X [N][I][T] f32 -> Xb [N*T][I] f16 (transpose) -----
__launch_bounds__(256)
__global__ void prep_x(const float* __restrict__ X, f16* __restrict__ Xb) {
    __shared__ float tile[64][65];
    const int n = blockIdx.z, i0 = blockIdx.y * 64, t0 = blockIdx.x * 64;
    const int tx = threadIdx.x & 63, q = threadIdx.x >> 6;
    const float* Xn = X + (size_t)n * II * TT;
#pragma unroll 4
    for (int j = 0; j < 16; ++j) {
        int il = j * 4 + q;
        int t = t0 + tx;
        tile[il][tx] = (t < TT) ? Xn[(size_t)(i0 + il) * TT + t] : 0.f;
    }
    __syncthreads();
#pragma unroll 4
    for (int j = 0; j < 16; ++j) {
        int tl = j * 4 + q;
        int t = t0 + tl;
        if (t < TT)
            Xb[((size_t)n * TT + t) * II + i0 + tx] = (f16)tile[tx][tl];
    }
}

// ---------------- prep: W1 -> f16 hi/lo [H][I] ------------------------------
__launch_bounds__(256)
__global__ void prep_w1(const float* __restrict__ W1, f16* __restrict__ Wh,
                        f16* __restrict__ Wl) {
    int idx = blockIdx.x * 256 + threadIdx.x;
    float w = W1[idx];
    f16 h = (f16)w;
    f16 l = (f16)(w - (float)h);
    Wh[idx] = h;
    Wl[idx] = l;
}

// ---------------- prep: W2 -> f16 hi/lo [32 padded][H] ----------------------
__launch_bounds__(256)
__global__ void prep_w2(const float* __restrict__ W2, f16* __restrict__ Wh,
                        f16* __restrict__ Wl) {
    int idx = blockIdx.x * 256 + threadIdx.x;
    int o = idx >> 10;
    float w = (o < OO) ? W2[idx] : 0.f;
    f16 h = (f16)w;
    f16 l = (f16)(w - (float)h);
    Wh[idx] = h;
    Wl[idx] = l;
}

// ---------------- FUSED layer 1: 128x128 tile, dbuf K-loop ------------------
// grid (8, 64), 256 thr. Per block: 4 t-chunks of 128.
// Chunk: prologue loads iter0 -> buf0; 8 K-iters [barrier; issue k+1 -> buf^;
// ds_read+MFMA buf]; epilogue->yb; scan (tid<128) stores spikes DIRECTLY to
// global (no pack phase, no yb write-back).
// LDS: yb 128x132 f32 = 67.6 KB, staging dbuf (2x24 KB) unioned at its base.
__launch_bounds__(256)
__global__ void gemm1_scan1(const f16* __restrict__ Xb, const f16* __restrict__ Wh,
                            const f16* __restrict__ Wl, f16* __restrict__ S1) {
    __shared__ __align__(16) char smem[128 * 132 * 4];  // 67,584 B
    float* yb = (float*)smem;

    const int tid = threadIdx.x;
    const int wave = tid >> 6, lane = tid & 63;

    // XCD swizzle: the 8 h-tiles of one n share an XCD
    const int f = blockIdx.y * 8 + blockIdx.x;
    const int x = f & 7, g = f >> 3;
    const int n = x * 8 + (g & 7);
    const int ht = g >> 3;
    const int h0g = ht * 128;

    const int rbl = wave * 32 + (lane >> 2);   // staged local row (A rows 0..127)
    const int koff = (lane & 3) * 8;
    const f16* gBh0 = Wh + (size_t)(h0g + rbl) * II + koff;
    const f16* gBl0 = Wl + (size_t)(h0g + rbl) * II + koff;

    const int wm = wave & 1, wn = wave >> 1;
    const int fr = lane & 15, kq = lane >> 4;

    float p1 = 0.f, a1 = 0.f, p2 = 0.f, a2 = 0.f;  // scan state (tid<128)

    for (int c = 0; c < 4; ++c) {
        const int t0 = c * 128;
        const int TCe = (TT - t0 < 128) ? (TT - t0) : 128;

        int r0 = rbl;      if (r0 > TCe - 1) r0 = TCe - 1;
        int r1 = rbl + 16; if (r1 > TCe - 1) r1 = TCe - 1;
        const f16* gA0 = Xb + ((size_t)n * TT + t0 + r0) * II + koff;
        const f16* gA1 = Xb + ((size_t)n * TT + t0 + r1) * II + koff;

        auto stage = [&](int kk2, int b) {
            f16* As_b = (f16*)(smem + b * 24576);
            f16* Bh_b = As_b + 4096;
            f16* Bl_b = As_b + 8192;
            const int ko = kk2 * 32;
            gl2lds16(gA0 + ko, As_b + wave * 1024);
            gl2lds16(gA1 + ko, As_b + wave * 1024 + 512);
            gl2lds16(gBh0 + ko, Bh_b + wave * 1024);
            gl2lds16(gBh0 + 16 * II + ko, Bh_b + wave * 1024 + 512);
            gl2lds16(gBl0 + ko, Bl_b + wave * 1024);
            gl2lds16(gBl0 + 16 * II + ko, Bl_b + wave * 1024 + 512);
        };

        stage(0, 0);  // previous chunk's post-scan barrier protects yb base

        f32x4 acc[4][4] = {};
        for (int kk = 0; kk < 8; ++kk) {
            __syncthreads();                 // buf[kk&1] DMA drained here
            if (kk < 7) stage(kk + 1, (kk + 1) & 1);

            const f16* As_b = (const f16*)(smem + (kk & 1) * 24576);
            const f16* Bh_b = As_b + 4096;
            const f16* Bl_b = As_b + 8192;

            f16x8 av[4], bhv[4], blv[4];
#pragma unroll
            for (int i = 0; i < 4; ++i) {
                av[i]  = *(const f16x8*)(As_b + (wm * 64 + i * 16 + fr) * 32 + kq * 8);
                bhv[i] = *(const f16x8*)(Bh_b + (wn * 64 + i * 16 + fr) * 32 + kq * 8);
                blv[i] = *(const f16x8*)(Bl_b + (wn * 64 + i * 16 + fr) * 32 + kq * 8);
            }
#pragma unroll
            for (int i = 0; i < 4; ++i)
#pragma unroll
                for (int j = 0; j < 4; ++j) {
                    acc[i][j] = __builtin_amdgcn_mfma_f32_16x16x32_f16(av[i], bhv[j], acc[i][j], 0, 0, 0);
                    acc[i][j] = __builtin_amdgcn_mfma_f32_16x16x32_f16(av[i], blv[j], acc[i][j], 0, 0, 0);
                }
        }
        __syncthreads();  // all frag reads done before epilogue overwrites staging

        // epilogue: acc -> yb (t-major, stride 132)
#pragma unroll
        for (int i = 0; i < 4; ++i)
#pragma unroll
            for (int j = 0; j < 4; ++j) {
                int tr = wm * 64 + i * 16 + kq * 4;
                int hc = wn * 64 + j * 16 + fr;
#pragma unroll
                for (int r = 0; r < 4; ++r)
                    yb[(tr + r) * 132 + hc] = acc[i][j][r];
            }
        __syncthreads();

        // sequential scan; 8-deep LDS prefetch ring; spikes -> global directly
        if (tid < 128) {
            f16* sq = S1 + ((size_t)n * TT + t0) * HH + h0g + tid;
            float rb_[8];
#pragma unroll
            for (int j = 0; j < 8; ++j) rb_[j] = yb[j * 132 + tid];
            int t = 0;
            for (; t + 8 <= TCe; t += 8) {
#pragma unroll
                for (int j = 0; j < 8; ++j) {
                    float xv = rb_[j];
                    int tn = t + j + 8;
                    rb_[j] = (tn < TCe) ? yb[tn * 132 + tid] : 0.f;
                    a1 = D_SR * (a1 + p1);
                    p1 = D_SR * p1 + xv;
                    float ut = C_SR * a1;
                    a2 = D_RF * (a2 + p2);
                    float u = ut + C_RF * a2;
                    float s = (u >= THETA) ? 1.0f : 0.0f;
                    p2 = D_RF * p2 + REFS * s;
                    sq[(size_t)(t + j) * HH] = (f16)s;
                }
            }
            int rem = TCe - t;
#pragma unroll
            for (int j = 0; j < 8; ++j) {
                if (j < rem) {
                    float xv = rb_[j];
                    a1 = D_SR * (a1 + p1);
                    p1 = D_SR * p1 + xv;
                    float ut = C_SR * a1;
                    a2 = D_RF * (a2 + p2);
                    float u = ut + C_RF * a2;
                    float s = (u >= THETA) ? 1.0f : 0.0f;
                    p2 = D_RF * p2 + REFS * s;
                    sq[(size_t)(t + j) * HH] = (f16)s;
                }
            }
        }
        __syncthreads();  // yb reads done; next chunk may restage over yb base
    }
}

// ---------------- GEMM2 (MFMA, split-f16, dbuf, split-K x2) -----------------
// grid (250, 2); 256 thr; tile 128 m x 32 o; K-half = 512, BK=32, 16 iters.
__launch_bounds__(256)
__global__ void gemm2_mfma(const f16* __restrict__ S1, const f16* __restrict__ W2h,
                           const f16* __restrict__ W2l, float* __restrict__ Y2) {
    __shared__ __align__(16) f16 As[2][128 * 32];  // 2 x 8 KB
    __shared__ __align__(16) f16 Bh[2][32 * 32];   // 2 x 2 KB
    __shared__ __align__(16) f16 Bl[2][32 * 32];   // 2 x 2 KB

    const int tid = threadIdx.x;
    const int wave = tid >> 6, lane = tid & 63;
    const int m0 = blockIdx.x * 128;
    const int kh = blockIdx.y;            // K half: 0 or 1
    const int kbase = kh * 512;           // f16 element offset in K
    const int fr = lane & 15, kq = lane >> 4;

    const f16* gA0 = S1 + (size_t)(m0 + wave * 32 + (lane >> 2)) * HH + kbase + (lane & 3) * 8;
    const f16* gA1 = gA0 + (size_t)16 * HH;
    const f16* gB = (wave < 2 ? W2h : W2l) + (size_t)((wave & 1) * 16 + (lane >> 2)) * HH + kbase + (lane & 3) * 8;

    auto stage = [&](int kk2, int b) {
        const int ko = kk2 * 32;
        gl2lds16(gA0 + ko, &As[b][wave * 1024]);
        gl2lds16(gA1 + ko, &As[b][wave * 1024 + 512]);
        gl2lds16(gB + ko, (wave < 2 ? &Bh[b][0] : &Bl[b][0]) + (wave & 1) * 512);
    };

    stage(0, 0);

    f32x4 acc[2][2] = {};
    for (int kk = 0; kk < 16; ++kk) {
        __syncthreads();
        if (kk < 15) stage(kk + 1, (kk + 1) & 1);
        const int b = kk & 1;

        f16x8 a[2], bh[2], bl[2];
#pragma unroll
        for (int i = 0; i < 2; ++i) {
            a[i]  = *(const f16x8*)(&As[b][(wave * 32 + i * 16 + fr) * 32 + kq * 8]);
            bh[i] = *(const f16x8*)(&Bh[b][(i * 16 + fr) * 32 + kq * 8]);
            bl[i] = *(const f16x8*)(&Bl[b][(i * 16 + fr) * 32 + kq * 8]);
        }
#pragma unroll
        for (int i = 0; i < 2; ++i)
#pragma unroll
            for (int j = 0; j < 2; ++j) {
                acc[i][j] = __builtin_amdgcn_mfma_f32_16x16x32_f16(a[i], bh[j], acc[i][j], 0, 0, 0);
                acc[i][j] = __builtin_amdgcn_mfma_f32_16x16x32_f16(a[i], bl[j], acc[i][j], 0, 0, 0);
            }
    }

    float* Yh = Y2 + (size_t)kh * NN * TT * 32;
#pragma unroll
    for (int i = 0; i < 2; ++i)
#pragma unroll
        for (int j = 0; j < 2; ++j) {
            int rbase = m0 + wave * 32 + i * 16 + kq * 4;
            int cc = j * 16 + fr;
            float* p = Yh + (size_t)rbase * 32 + cc;
#pragma unroll
            for (int r = 0; r < 4; ++r)
                p[(size_t)r * 32] = acc[i][j][r];
        }
}

// ---------------- scan2: y2a+y2b [N*T][32] f32 -> out [N][O][T] -------------
#define PF2 16
__launch_bounds__(64)
__global__ void scan2_k(const float* __restrict__ Y2, float* __restrict__ Out) {
    __shared__ float sb[OO * TT];
    const int n = blockIdx.x, lane = threadIdx.x;
    const float* ya = Y2 + (size_t)n * TT * 32;
    const float* yb2 = Y2 + (size_t)NN * TT * 32 + (size_t)n * TT * 32;
    const bool act = (lane < 32);

    float p1 = 0.f, a1 = 0.f, p2 = 0.f, a2 = 0.f;
    float buf[PF2];
#pragma unroll
    for (int j = 0; j < PF2; ++j)
        buf[j] = act ? (ya[j * 32 + lane] + yb2[j * 32 + lane]) : 0.f;

    int t = 0;
    for (; t + PF2 <= TT; t += PF2) {
#pragma unroll
        for (int j = 0; j < PF2; ++j) {
            float x = buf[j];
            int tn = t + j + PF2;
            buf[j] = (act && tn < TT) ? (ya[tn * 32 + lane] + yb2[tn * 32 + lane]) : 0.f;
            a1 = D_SR * (a1 + p1);
            p1 = D_SR * p1 + x;
            float ut = C_SR * a1;
            a2 = D_RF * (a2 + p2);
            float u = ut + C_RF * a2;
            float s = (u >= THETA) ? 1.0f : 0.0f;
            p2 = D_RF * p2 + REFS * s;
            if (lane < OO) sb[lane * TT + t + j] = s;
        }
    }
#pragma unroll
    for (int j = 0; j < PF2; ++j) {
        if (t + j < TT) {
            float x = buf[j];
            a1 = D_SR * (a1 + p1);
            p1 = D_SR * p1 + x;
            float ut = C_SR * a1;
            a2 = D_RF * (a2 + p2);
            float u = ut + C_RF * a2;
            float s = (u >= THETA) ? 1.0f : 0.0f;
            p2 = D_RF * p2 + REFS * s;
            if (lane < OO) sb[lane * TT + t + j] = s;
        }
    }
    __syncthreads();
    float* on = Out + (size_t)n * OO * TT;
    for (int e = lane; e < OO * TT; e += 64) on[e] = sb[e];
}

extern "C" void kernel_launch(void* const* d_in, const int* in_sizes, int n_in,
                              void* d_out, int out_size, void* d_ws, size_t ws_size,
                              hipStream_t stream) {
    const float* X  = (const float*)d_in[0];
    const float* W1 = (const float*)d_in[1];
    const float* W2 = (const float*)d_in[2];
    float* out = (float*)d_out;

    const size_t s_s1 = (size_t)NN * TT * HH * 2;   // 65,536,000
    const size_t s_Xb = (size_t)NN * TT * II * 2;   // 16,384,000
    const size_t s_W  = (size_t)HH * II * 2;        //    524,288 (x2)
    const size_t s_W2 = (size_t)32 * HH * 2;        //     65,536 (x2)
    // + y2 halves 2 x 4,096,000 => ~91.3 MB total

    char* w = (char*)d_ws;
    f16*   s1b = (f16*)w;  w += s_s1;
    f16*   Xb  = (f16*)w;  w += s_Xb;
    f16*   W1h = (f16*)w;  w += s_W;
    f16*   W1l = (f16*)w;  w += s_W;
    f16*   W2h = (f16*)w;  w += s_W2;
    f16*   W2l = (f16*)w;  w += s_W2;
    float* y2  = (float*)w;

    prep_x<<<dim3(8, 4, NN), 256, 0, stream>>>(X, Xb);
    prep_w1<<<(HH * II) / 256, 256, 0, stream>>>(W1, W1h, W1l);
    prep_w2<<<(32 * HH) / 256, 256, 0, stream>>>(W2, W2h, W2l);

    gemm1_scan1<<<dim3(8, NN), 256, 0, stream>>>(Xb, W1h, W1l, s1b);

    gemm2_mfma<<<dim3((NN * TT) / 128, 2), 256, 0, stream>>>(s1b, W2h, W2l, y2);
    scan2_k<<<NN, 64, 0, stream>>>(y2, out);
}

// Round 10
// 240.621 us; speedup vs baseline: 1.3592x; 1.3592x over previous
//
#include <hip/hip_runtime.h>

// SNN forward: [GEMM1+scan1 fused, 128x128, dbuf K-loop, direct-global spike
// store] -> GEMM2 (dbuf) -> scan2 (LDS-staged, ring-prefetched).
// f16 split-2: W = hi + lo (both f16), residual ~2^-24 => fp32-grade MFMA.
// X and spikes are exact in f16.

#define NN 64
#define II 256
#define HH 1024
#define OO 18
#define TT 500

#define D_SR 0.9048374180359595f   // exp(-1/10)
#define C_SR 0.27182818284590454f  // e/10
#define D_RF 0.36787944117144233f  // exp(-1)
#define C_RF 2.718281828459045f    // e
#define THETA 10.0f
#define REFS (-20.0f)

typedef _Float16 f16;
typedef _Float16 f16x2 __attribute__((ext_vector_type(2)));
typedef _Float16 f16x8 __attribute__((ext_vector_type(8)));
typedef float f32x4 __attribute__((ext_vector_type(4)));

__device__ __forceinline__ void gl2lds16(const void* g, void* l) {
    __builtin_amdgcn_global_load_lds(
        (const __attribute__((address_space(1))) void*)g,
        (__attribute__((address_space(3))) void*)l, 16, 0, 0);
}

// ---------------- prep: X [N][I][T] f32 -> Xb [N*T][I] f16 (transpose) -----
__launch_bounds__(256)
__global__ void prep_x(const float* __restrict__ X, f16* __restrict__ Xb) {
    __shared__ float tile[64][65];
    const int n = blockIdx.z, i0 = blockIdx.y * 64, t0 = blockIdx.x * 64;
    const int tx = threadIdx.x & 63, q = threadIdx.x >> 6;
    const float* Xn = X + (size_t)n * II * TT;
#pragma unroll 4
    for (int j = 0; j < 16; ++j) {
        int il = j * 4 + q;
        int t = t0 + tx;
        tile[il][tx] = (t < TT) ? Xn[(size_t)(i0 + il) * TT + t] : 0.f;
    }
    __syncthreads();
#pragma unroll 4
    for (int j = 0; j < 16; ++j) {
        int tl = j * 4 + q;
        int t = t0 + tl;
        if (t < TT)
            Xb[((size_t)n * TT + t) * II + i0 + tx] = (f16)tile[tx][tl];
    }
}

// ---------------- prep: W1 -> f16 hi/lo [H][I] ------------------------------
__launch_bounds__(256)
__global__ void prep_w1(const float* __restrict__ W1, f16* __restrict__ Wh,
                        f16* __restrict__ Wl) {
    int idx = blockIdx.x * 256 + threadIdx.x;
    float w = W1[idx];
    f16 h = (f16)w;
    f16 l = (f16)(w - (float)h);
    Wh[idx] = h;
    Wl[idx] = l;
}

// ---------------- prep: W2 -> f16 hi/lo [32 padded][H] ----------------------
__launch_bounds__(256)
__global__ void prep_w2(const float* __restrict__ W2, f16* __restrict__ Wh,
                        f16* __restrict__ Wl) {
    int idx = blockIdx.x * 256 + threadIdx.x;
    int o = idx >> 10;
    float w = (o < OO) ? W2[idx] : 0.f;
    f16 h = (f16)w;
    f16 l = (f16)(w - (float)h);
    Wh[idx] = h;
    Wl[idx] = l;
}

// ---------------- FUSED layer 1: 128x128 tile, dbuf K-loop ------------------
__launch_bounds__(256)
__global__ void gemm1_scan1(const f16* __restrict__ Xb, const f16* __restrict__ Wh,
                            const f16* __restrict__ Wl, f16* __restrict__ S1) {
    __shared__ __align__(16) char smem[128 * 132 * 4];  // 67,584 B
    float* yb = (float*)smem;

    const int tid = threadIdx.x;
    const int wave = tid >> 6, lane = tid & 63;

    // XCD swizzle: the 8 h-tiles of one n share an XCD
    const int f = blockIdx.y * 8 + blockIdx.x;
    const int x = f & 7, g = f >> 3;
    const int n = x * 8 + (g & 7);
    const int ht = g >> 3;
    const int h0g = ht * 128;

    const int rbl = wave * 32 + (lane >> 2);
    const int koff = (lane & 3) * 8;
    const f16* gBh0 = Wh + (size_t)(h0g + rbl) * II + koff;
    const f16* gBl0 = Wl + (size_t)(h0g + rbl) * II + koff;

    const int wm = wave & 1, wn = wave >> 1;
    const int fr = lane & 15, kq = lane >> 4;

    float p1 = 0.f, a1 = 0.f, p2 = 0.f, a2 = 0.f;  // scan state (tid<128)

    for (int c = 0; c < 4; ++c) {
        const int t0 = c * 128;
        const int TCe = (TT - t0 < 128) ? (TT - t0) : 128;

        int r0 = rbl;      if (r0 > TCe - 1) r0 = TCe - 1;
        int r1 = rbl + 16; if (r1 > TCe - 1) r1 = TCe - 1;
        const f16* gA0 = Xb + ((size_t)n * TT + t0 + r0) * II + koff;
        const f16* gA1 = Xb + ((size_t)n * TT + t0 + r1) * II + koff;

        auto stage = [&](int kk2, int b) {
            f16* As_b = (f16*)(smem + b * 24576);
            f16* Bh_b = As_b + 4096;
            f16* Bl_b = As_b + 8192;
            const int ko = kk2 * 32;
            gl2lds16(gA0 + ko, As_b + wave * 1024);
            gl2lds16(gA1 + ko, As_b + wave * 1024 + 512);
            gl2lds16(gBh0 + ko, Bh_b + wave * 1024);
            gl2lds16(gBh0 + 16 * II + ko, Bh_b + wave * 1024 + 512);
            gl2lds16(gBl0 + ko, Bl_b + wave * 1024);
            gl2lds16(gBl0 + 16 * II + ko, Bl_b + wave * 1024 + 512);
        };

        stage(0, 0);

        f32x4 acc[4][4] = {};
        for (int kk = 0; kk < 8; ++kk) {
            __syncthreads();                 // buf[kk&1] DMA drained here
            if (kk < 7) stage(kk + 1, (kk + 1) & 1);

            const f16* As_b = (const f16*)(smem + (kk & 1) * 24576);
            const f16* Bh_b = As_b + 4096;
            const f16* Bl_b = As_b + 8192;

            f16x8 av[4], bhv[4], blv[4];
#pragma unroll
            for (int i = 0; i < 4; ++i) {
                av[i]  = *(const f16x8*)(As_b + (wm * 64 + i * 16 + fr) * 32 + kq * 8);
                bhv[i] = *(const f16x8*)(Bh_b + (wn * 64 + i * 16 + fr) * 32 + kq * 8);
                blv[i] = *(const f16x8*)(Bl_b + (wn * 64 + i * 16 + fr) * 32 + kq * 8);
            }
#pragma unroll
            for (int i = 0; i < 4; ++i)
#pragma unroll
                for (int j = 0; j < 4; ++j) {
                    acc[i][j] = __builtin_amdgcn_mfma_f32_16x16x32_f16(av[i], bhv[j], acc[i][j], 0, 0, 0);
                    acc[i][j] = __builtin_amdgcn_mfma_f32_16x16x32_f16(av[i], blv[j], acc[i][j], 0, 0, 0);
                }
        }
        __syncthreads();

        // epilogue: acc -> yb (t-major, stride 132)
#pragma unroll
        for (int i = 0; i < 4; ++i)
#pragma unroll
            for (int j = 0; j < 4; ++j) {
                int tr = wm * 64 + i * 16 + kq * 4;
                int hc = wn * 64 + j * 16 + fr;
#pragma unroll
                for (int r = 0; r < 4; ++r)
                    yb[(tr + r) * 132 + hc] = acc[i][j][r];
            }
        __syncthreads();

        // sequential scan; 8-deep LDS prefetch ring; spikes -> global directly
        if (tid < 128) {
            f16* sq = S1 + ((size_t)n * TT + t0) * HH + h0g + tid;
            float rb_[8];
#pragma unroll
            for (int j = 0; j < 8; ++j) rb_[j] = yb[j * 132 + tid];
            int t = 0;
            for (; t + 8 <= TCe; t += 8) {
#pragma unroll
                for (int j = 0; j < 8; ++j) {
                    float xv = rb_[j];
                    int tn = t + j + 8;
                    rb_[j] = (tn < TCe) ? yb[tn * 132 + tid] : 0.f;
                    a1 = D_SR * (a1 + p1);
                    p1 = D_SR * p1 + xv;
                    float ut = C_SR * a1;
                    a2 = D_RF * (a2 + p2);
                    float u = ut + C_RF * a2;
                    float s = (u >= THETA) ? 1.0f : 0.0f;
                    p2 = D_RF * p2 + REFS * s;
                    sq[(size_t)(t + j) * HH] = (f16)s;
                }
            }
            int rem = TCe - t;
#pragma unroll
            for (int j = 0; j < 8; ++j) {
                if (j < rem) {
                    float xv = rb_[j];
                    a1 = D_SR * (a1 + p1);
                    p1 = D_SR * p1 + xv;
                    float ut = C_SR * a1;
                    a2 = D_RF * (a2 + p2);
                    float u = ut + C_RF * a2;
                    float s = (u >= THETA) ? 1.0f : 0.0f;
                    p2 = D_RF * p2 + REFS * s;
                    sq[(size_t)(t + j) * HH] = (f16)s;
                }
            }
        }
        __syncthreads();
    }
}

// ---------------- GEMM2 (MFMA, split-f16, dbuf K-loop) ----------------------
// grid 250; 256 thr; tile 128 m x 32 o; K=1024, BK=32.
__launch_bounds__(256)
__global__ void gemm2_mfma(const f16* __restrict__ S1, const f16* __restrict__ W2h,
                           const f16* __restrict__ W2l, float* __restrict__ Y2) {
    __shared__ __align__(16) f16 As[2][128 * 32];
    __shared__ __align__(16) f16 Bh[2][32 * 32];
    __shared__ __align__(16) f16 Bl[2][32 * 32];

    const int tid = threadIdx.x;
    const int wave = tid >> 6, lane = tid & 63;
    const int m0 = blockIdx.x * 128;
    const int fr = lane & 15, kq = lane >> 4;

    const f16* gA0 = S1 + (size_t)(m0 + wave * 32 + (lane >> 2)) * HH + (lane & 3) * 8;
    const f16* gA1 = gA0 + (size_t)16 * HH;
    const f16* gB = (wave < 2 ? W2h : W2l) + (size_t)((wave & 1) * 16 + (lane >> 2)) * HH + (lane & 3) * 8;

    auto stage = [&](int kk2, int b) {
        const int ko = kk2 * 32;
        gl2lds16(gA0 + ko, &As[b][wave * 1024]);
        gl2lds16(gA1 + ko, &As[b][wave * 1024 + 512]);
        gl2lds16(gB + ko, (wave < 2 ? &Bh[b][0] : &Bl[b][0]) + (wave & 1) * 512);
    };

    stage(0, 0);

    f32x4 acc[2][2] = {};
    for (int kk = 0; kk < HH / 32; ++kk) {
        __syncthreads();
        if (kk < HH / 32 - 1) stage(kk + 1, (kk + 1) & 1);
        const int b = kk & 1;

        f16x8 a[2], bh[2], bl[2];
#pragma unroll
        for (int i = 0; i < 2; ++i) {
            a[i]  = *(const f16x8*)(&As[b][(wave * 32 + i * 16 + fr) * 32 + kq * 8]);
            bh[i] = *(const f16x8*)(&Bh[b][(i * 16 + fr) * 32 + kq * 8]);
            bl[i] = *(const f16x8*)(&Bl[b][(i * 16 + fr) * 32 + kq * 8]);
        }
#pragma unroll
        for (int i = 0; i < 2; ++i)
#pragma unroll
            for (int j = 0; j < 2; ++j) {
                acc[i][j] = __builtin_amdgcn_mfma_f32_16x16x32_f16(a[i], bh[j], acc[i][j], 0, 0, 0);
                acc[i][j] = __builtin_amdgcn_mfma_f32_16x16x32_f16(a[i], bl[j], acc[i][j], 0, 0, 0);
            }
    }

#pragma unroll
    for (int i = 0; i < 2; ++i)
#pragma unroll
        for (int j = 0; j < 2; ++j) {
            int rbase = m0 + wave * 32 + i * 16 + kq * 4;
            int cc = j * 16 + fr;
            float* p = Y2 + (size_t)rbase * 32 + cc;
#pragma unroll
            for (int r = 0; r < 4; ++r)
                p[(size_t)r * 32] = acc[i][j][r];
        }
}

// ---------------- scan2: LDS-staged. y2 [N*T][32] f32 -> out [N][O][T] ------
// grid 64 (n), 256 thr. 2 chunks of 250 t: bulk-coalesced float4 load into
// LDS, then 32 lanes scan from LDS with an 8-deep register ring (no global
// latency in the serial path).
__launch_bounds__(256)
__global__ void scan2_k(const float* __restrict__ Y2, float* __restrict__ Out) {
    __shared__ float yc[250 * 32];   // 32,000 B
    __shared__ float sb[OO * TT];    // 36,000 B
    const int n = blockIdx.x, tid = threadIdx.x;

    float p1 = 0.f, a1 = 0.f, p2 = 0.f, a2 = 0.f;  // scan state (tid<32)

    for (int half = 0; half < 2; ++half) {
        // cooperative load: 250*32 floats = 2000 float4 / 256 thr
        const float4* src = (const float4*)(Y2 + ((size_t)n * TT + half * 250) * 32);
        float4* dst = (float4*)yc;
        for (int i = tid; i < 2000; i += 256) dst[i] = src[i];
        __syncthreads();

        if (tid < 32) {
            float rb_[8];
#pragma unroll
            for (int j = 0; j < 8; ++j) rb_[j] = yc[j * 32 + tid];
            for (int t = 0; t < 250; ++t) {
                float xv = rb_[t & 7];
                int tn = t + 8;
                rb_[t & 7] = (tn < 250) ? yc[tn * 32 + tid] : 0.f;
                a1 = D_SR * (a1 + p1);
                p1 = D_SR * p1 + xv;
                float ut = C_SR * a1;
                a2 = D_RF * (a2 + p2);
                float u = ut + C_RF * a2;
                float s = (u >= THETA) ? 1.0f : 0.0f;
                p2 = D_RF * p2 + REFS * s;
                if (tid < OO) sb[tid * TT + half * 250 + t] = s;
            }
        }
        __syncthreads();  // yc reads done before next half's load
    }

    float* on = Out + (size_t)n * OO * TT;
    for (int e = tid; e < OO * TT; e += 256) on[e] = sb[e];
}

extern "C" void kernel_launch(void* const* d_in, const int* in_sizes, int n_in,
                              void* d_out, int out_size, void* d_ws, size_t ws_size,
                              hipStream_t stream) {
    const float* X  = (const float*)d_in[0];
    const float* W1 = (const float*)d_in[1];
    const float* W2 = (const float*)d_in[2];
    float* out = (float*)d_out;

    const size_t s_s1 = (size_t)NN * TT * HH * 2;   // 65,536,000
    const size_t s_Xb = (size_t)NN * TT * II * 2;   // 16,384,000
    const size_t s_W  = (size_t)HH * II * 2;        //    524,288 (x2)
    const size_t s_W2 = (size_t)32 * HH * 2;        //     65,536 (x2)
    // + y2 4,096,000 => ~87 MB total

    char* w = (char*)d_ws;
    f16*   s1b = (f16*)w;  w += s_s1;
    f16*   Xb  = (f16*)w;  w += s_Xb;
    f16*   W1h = (f16*)w;  w += s_W;
    f16*   W1l = (f16*)w;  w += s_W;
    f16*   W2h = (f16*)w;  w += s_W2;
    f16*   W2l = (f16*)w;  w += s_W2;
    float* y2  = (float*)w;

    prep_x<<<dim3(8, 4, NN), 256, 0, stream>>>(X, Xb);
    prep_w1<<<(HH * II) / 256, 256, 0, stream>>>(W1, W1h, W1l);
    prep_w2<<<(32 * HH) / 256, 256, 0, stream>>>(W2, W2h, W2l);

    gemm1_scan1<<<dim3(8, NN), 256, 0, stream>>>(Xb, W1h, W1l, s1b);

    gemm2_mfma<<<(NN * TT) / 128, 256, 0, stream>>>(s1b, W2h, W2l, y2);
    scan2_k<<<NN, 256, 0, stream>>>(y2, out);
}

// Round 11
// 196.060 us; speedup vs baseline: 1.6681x; 1.2273x over previous
//
#include <hip/hip_runtime.h>

// SNN forward: [GEMM1+scan1 fused, 128x128, dbuf K-loop, direct-global spike
// store] -> GEMM2 (dbuf) -> scan2 (LDS-staged, STATIC-index ring).
// f16 split-2: W = hi + lo (both f16), residual ~2^-24 => fp32-grade MFMA.
// X and spikes are exact in f16.
// NOTE: ring buffers must be indexed by compile-time constants (unrolled),
// else the compiler demotes them to scratch (~400 cyc/step — measured R9).

#define NN 64
#define II 256
#define HH 1024
#define OO 18
#define TT 500

#define D_SR 0.9048374180359595f   // exp(-1/10)
#define C_SR 0.27182818284590454f  // e/10
#define D_RF 0.36787944117144233f  // exp(-1)
#define C_RF 2.718281828459045f    // e
#define THETA 10.0f
#define REFS (-20.0f)

typedef _Float16 f16;
typedef _Float16 f16x2 __attribute__((ext_vector_type(2)));
typedef _Float16 f16x8 __attribute__((ext_vector_type(8)));
typedef float f32x4 __attribute__((ext_vector_type(4)));

__device__ __forceinline__ void gl2lds16(const void* g, void* l) {
    __builtin_amdgcn_global_load_lds(
        (const __attribute__((address_space(1))) void*)g,
        (__attribute__((address_space(3))) void*)l, 16, 0, 0);
}

// ---------------- prep: X [N][I][T] f32 -> Xb [N*T][I] f16 (transpose) -----
__launch_bounds__(256)
__global__ void prep_x(const float* __restrict__ X, f16* __restrict__ Xb) {
    __shared__ float tile[64][65];
    const int n = blockIdx.z, i0 = blockIdx.y * 64, t0 = blockIdx.x * 64;
    const int tx = threadIdx.x & 63, q = threadIdx.x >> 6;
    const float* Xn = X + (size_t)n * II * TT;
#pragma unroll 4
    for (int j = 0; j < 16; ++j) {
        int il = j * 4 + q;
        int t = t0 + tx;
        tile[il][tx] = (t < TT) ? Xn[(size_t)(i0 + il) * TT + t] : 0.f;
    }
    __syncthreads();
#pragma unroll 4
    for (int j = 0; j < 16; ++j) {
        int tl = j * 4 + q;
        int t = t0 + tl;
        if (t < TT)
            Xb[((size_t)n * TT + t) * II + i0 + tx] = (f16)tile[tx][tl];
    }
}

// ---------------- prep: W1 -> f16 hi/lo [H][I] ------------------------------
__launch_bounds__(256)
__global__ void prep_w1(const float* __restrict__ W1, f16* __restrict__ Wh,
                        f16* __restrict__ Wl) {
    int idx = blockIdx.x * 256 + threadIdx.x;
    float w = W1[idx];
    f16 h = (f16)w;
    f16 l = (f16)(w - (float)h);
    Wh[idx] = h;
    Wl[idx] = l;
}

// ---------------- prep: W2 -> f16 hi/lo [32 padded][H] ----------------------
__launch_bounds__(256)
__global__ void prep_w2(const float* __restrict__ W2, f16* __restrict__ Wh,
                        f16* __restrict__ Wl) {
    int idx = blockIdx.x * 256 + threadIdx.x;
    int o = idx >> 10;
    float w = (o < OO) ? W2[idx] : 0.f;
    f16 h = (f16)w;
    f16 l = (f16)(w - (float)h);
    Wh[idx] = h;
    Wl[idx] = l;
}

// ---------------- FUSED layer 1: 128x128 tile, dbuf K-loop ------------------
__launch_bounds__(256)
__global__ void gemm1_scan1(const f16* __restrict__ Xb, const f16* __restrict__ Wh,
                            const f16* __restrict__ Wl, f16* __restrict__ S1) {
    __shared__ __align__(16) char smem[128 * 132 * 4];  // 67,584 B
    float* yb = (float*)smem;

    const int tid = threadIdx.x;
    const int wave = tid >> 6, lane = tid & 63;

    // XCD swizzle: the 8 h-tiles of one n share an XCD
    const int f = blockIdx.y * 8 + blockIdx.x;
    const int x = f & 7, g = f >> 3;
    const int n = x * 8 + (g & 7);
    const int ht = g >> 3;
    const int h0g = ht * 128;

    const int rbl = wave * 32 + (lane >> 2);
    const int koff = (lane & 3) * 8;
    const f16* gBh0 = Wh + (size_t)(h0g + rbl) * II + koff;
    const f16* gBl0 = Wl + (size_t)(h0g + rbl) * II + koff;

    const int wm = wave & 1, wn = wave >> 1;
    const int fr = lane & 15, kq = lane >> 4;

    float p1 = 0.f, a1 = 0.f, p2 = 0.f, a2 = 0.f;  // scan state (tid<128)

    for (int c = 0; c < 4; ++c) {
        const int t0 = c * 128;
        const int TCe = (TT - t0 < 128) ? (TT - t0) : 128;

        int r0 = rbl;      if (r0 > TCe - 1) r0 = TCe - 1;
        int r1 = rbl + 16; if (r1 > TCe - 1) r1 = TCe - 1;
        const f16* gA0 = Xb + ((size_t)n * TT + t0 + r0) * II + koff;
        const f16* gA1 = Xb + ((size_t)n * TT + t0 + r1) * II + koff;

        auto stage = [&](int kk2, int b) {
            f16* As_b = (f16*)(smem + b * 24576);
            f16* Bh_b = As_b + 4096;
            f16* Bl_b = As_b + 8192;
            const int ko = kk2 * 32;
            gl2lds16(gA0 + ko, As_b + wave * 1024);
            gl2lds16(gA1 + ko, As_b + wave * 1024 + 512);
            gl2lds16(gBh0 + ko, Bh_b + wave * 1024);
            gl2lds16(gBh0 + 16 * II + ko, Bh_b + wave * 1024 + 512);
            gl2lds16(gBl0 + ko, Bl_b + wave * 1024);
            gl2lds16(gBl0 + 16 * II + ko, Bl_b + wave * 1024 + 512);
        };

        stage(0, 0);

        f32x4 acc[4][4] = {};
        for (int kk = 0; kk < 8; ++kk) {
            __syncthreads();                 // buf[kk&1] DMA drained here
            if (kk < 7) stage(kk + 1, (kk + 1) & 1);

            const f16* As_b = (const f16*)(smem + (kk & 1) * 24576);
            const f16* Bh_b = As_b + 4096;
            const f16* Bl_b = As_b + 8192;

            f16x8 av[4], bhv[4], blv[4];
#pragma unroll
            for (int i = 0; i < 4; ++i) {
                av[i]  = *(const f16x8*)(As_b + (wm * 64 + i * 16 + fr) * 32 + kq * 8);
                bhv[i] = *(const f16x8*)(Bh_b + (wn * 64 + i * 16 + fr) * 32 + kq * 8);
                blv[i] = *(const f16x8*)(Bl_b + (wn * 64 + i * 16 + fr) * 32 + kq * 8);
            }
#pragma unroll
            for (int i = 0; i < 4; ++i)
#pragma unroll
                for (int j = 0; j < 4; ++j) {
                    acc[i][j] = __builtin_amdgcn_mfma_f32_16x16x32_f16(av[i], bhv[j], acc[i][j], 0, 0, 0);
                    acc[i][j] = __builtin_amdgcn_mfma_f32_16x16x32_f16(av[i], blv[j], acc[i][j], 0, 0, 0);
                }
        }
        __syncthreads();

        // epilogue: acc -> yb (t-major, stride 132)
#pragma unroll
        for (int i = 0; i < 4; ++i)
#pragma unroll
            for (int j = 0; j < 4; ++j) {
                int tr = wm * 64 + i * 16 + kq * 4;
                int hc = wn * 64 + j * 16 + fr;
#pragma unroll
                for (int r = 0; r < 4; ++r)
                    yb[(tr + r) * 132 + hc] = acc[i][j][r];
            }
        __syncthreads();

        // sequential scan; 8-deep LDS prefetch ring; spikes -> global directly
        if (tid < 128) {
            f16* sq = S1 + ((size_t)n * TT + t0) * HH + h0g + tid;
            float rb_[8];
#pragma unroll
            for (int j = 0; j < 8; ++j) rb_[j] = yb[j * 132 + tid];
            int t = 0;
            for (; t + 8 <= TCe; t += 8) {
#pragma unroll
                for (int j = 0; j < 8; ++j) {
                    float xv = rb_[j];
                    int tn = t + j + 8;
                    rb_[j] = (tn < TCe) ? yb[tn * 132 + tid] : 0.f;
                    a1 = D_SR * (a1 + p1);
                    p1 = D_SR * p1 + xv;
                    float ut = C_SR * a1;
                    a2 = D_RF * (a2 + p2);
                    float u = ut + C_RF * a2;
                    float s = (u >= THETA) ? 1.0f : 0.0f;
                    p2 = D_RF * p2 + REFS * s;
                    sq[(size_t)(t + j) * HH] = (f16)s;
                }
            }
            int rem = TCe - t;
#pragma unroll
            for (int j = 0; j < 8; ++j) {
                if (j < rem) {
                    float xv = rb_[j];
                    a1 = D_SR * (a1 + p1);
                    p1 = D_SR * p1 + xv;
                    float ut = C_SR * a1;
                    a2 = D_RF * (a2 + p2);
                    float u = ut + C_RF * a2;
                    float s = (u >= THETA) ? 1.0f : 0.0f;
                    p2 = D_RF * p2 + REFS * s;
                    sq[(size_t)(t + j) * HH] = (f16)s;
                }
            }
        }
        __syncthreads();
    }
}

// ---------------- GEMM2 (MFMA, split-f16, dbuf K-loop) ----------------------
// grid 250; 256 thr; tile 128 m x 32 o; K=1024, BK=32.
__launch_bounds__(256)
__global__ void gemm2_mfma(const f16* __restrict__ S1, const f16* __restrict__ W2h,
                           const f16* __restrict__ W2l, float* __restrict__ Y2) {
    __shared__ __align__(16) f16 As[2][128 * 32];
    __shared__ __align__(16) f16 Bh[2][32 * 32];
    __shared__ __align__(16) f16 Bl[2][32 * 32];

    const int tid = threadIdx.x;
    const int wave = tid >> 6, lane = tid & 63;
    const int m0 = blockIdx.x * 128;
    const int fr = lane & 15, kq = lane >> 4;

    const f16* gA0 = S1 + (size_t)(m0 + wave * 32 + (lane >> 2)) * HH + (lane & 3) * 8;
    const f16* gA1 = gA0 + (size_t)16 * HH;
    const f16* gB = (wave < 2 ? W2h : W2l) + (size_t)((wave & 1) * 16 + (lane >> 2)) * HH + (lane & 3) * 8;

    auto stage = [&](int kk2, int b) {
        const int ko = kk2 * 32;
        gl2lds16(gA0 + ko, &As[b][wave * 1024]);
        gl2lds16(gA1 + ko, &As[b][wave * 1024 + 512]);
        gl2lds16(gB + ko, (wave < 2 ? &Bh[b][0] : &Bl[b][0]) + (wave & 1) * 512);
    };

    stage(0, 0);

    f32x4 acc[2][2] = {};
    for (int kk = 0; kk < HH / 32; ++kk) {
        __syncthreads();
        if (kk < HH / 32 - 1) stage(kk + 1, (kk + 1) & 1);
        const int b = kk & 1;

        f16x8 a[2], bh[2], bl[2];
#pragma unroll
        for (int i = 0; i < 2; ++i) {
            a[i]  = *(const f16x8*)(&As[b][(wave * 32 + i * 16 + fr) * 32 + kq * 8]);
            bh[i] = *(const f16x8*)(&Bh[b][(i * 16 + fr) * 32 + kq * 8]);
            bl[i] = *(const f16x8*)(&Bl[b][(i * 16 + fr) * 32 + kq * 8]);
        }
#pragma unroll
        for (int i = 0; i < 2; ++i)
#pragma unroll
            for (int j = 0; j < 2; ++j) {
                acc[i][j] = __builtin_amdgcn_mfma_f32_16x16x32_f16(a[i], bh[j], acc[i][j], 0, 0, 0);
                acc[i][j] = __builtin_amdgcn_mfma_f32_16x16x32_f16(a[i], bl[j], acc[i][j], 0, 0, 0);
            }
    }

#pragma unroll
    for (int i = 0; i < 2; ++i)
#pragma unroll
        for (int j = 0; j < 2; ++j) {
            int rbase = m0 + wave * 32 + i * 16 + kq * 4;
            int cc = j * 16 + fr;
            float* p = Y2 + (size_t)rbase * 32 + cc;
#pragma unroll
            for (int r = 0; r < 4; ++r)
                p[(size_t)r * 32] = acc[i][j][r];
        }
}

// ---------------- scan2: LDS-staged, static-index ring ----------------------
// grid 64 (n), 256 thr. 2 chunks of 250 t: bulk-coalesced float4 load into
// LDS, then 32 lanes scan from LDS with an 8-deep UNROLLED register ring.
__launch_bounds__(256)
__global__ void scan2_k(const float* __restrict__ Y2, float* __restrict__ Out) {
    __shared__ float yc[250 * 32];   // 32,000 B
    __shared__ float sb[OO * TT];    // 36,000 B
    const int n = blockIdx.x, tid = threadIdx.x;

    float p1 = 0.f, a1 = 0.f, p2 = 0.f, a2 = 0.f;  // scan state (tid<32)

    for (int half = 0; half < 2; ++half) {
        // cooperative load: 250*32 floats = 2000 float4 / 256 thr
        const float4* src = (const float4*)(Y2 + ((size_t)n * TT + half * 250) * 32);
        float4* dst = (float4*)yc;
        for (int i = tid; i < 2000; i += 256) dst[i] = src[i];
        __syncthreads();

        if (tid < 32) {
            float rb_[8];
#pragma unroll
            for (int j = 0; j < 8; ++j) rb_[j] = yc[j * 32 + tid];
            int t = 0;
            for (; t + 8 <= 250; t += 8) {
#pragma unroll
                for (int j = 0; j < 8; ++j) {
                    float xv = rb_[j];
                    int tn = t + j + 8;
                    rb_[j] = (tn < 250) ? yc[tn * 32 + tid] : 0.f;
                    a1 = D_SR * (a1 + p1);
                    p1 = D_SR * p1 + xv;
                    float ut = C_SR * a1;
                    a2 = D_RF * (a2 + p2);
                    float u = ut + C_RF * a2;
                    float s = (u >= THETA) ? 1.0f : 0.0f;
                    p2 = D_RF * p2 + REFS * s;
                    if (tid < OO) sb[tid * TT + half * 250 + t + j] = s;
                }
            }
            // tail: 250 - 248 = 2 steps, static unroll
#pragma unroll
            for (int j = 0; j < 8; ++j) {
                if (t + j < 250) {
                    float xv = rb_[j];
                    a1 = D_SR * (a1 + p1);
                    p1 = D_SR * p1 + xv;
                    float ut = C_SR * a1;
                    a2 = D_RF * (a2 + p2);
                    float u = ut + C_RF * a2;
                    float s = (u >= THETA) ? 1.0f : 0.0f;
                    p2 = D_RF * p2 + REFS * s;
                    if (tid < OO) sb[tid * TT + half * 250 + t + j] = s;
                }
            }
        }
        __syncthreads();  // yc reads done before next half's load
    }

    float* on = Out + (size_t)n * OO * TT;
    for (int e = tid; e < OO * TT; e += 256) on[e] = sb[e];
}

extern "C" void kernel_launch(void* const* d_in, const int* in_sizes, int n_in,
                              void* d_out, int out_size, void* d_ws, size_t ws_size,
                              hipStream_t stream) {
    const float* X  = (const float*)d_in[0];
    const float* W1 = (const float*)d_in[1];
    const float* W2 = (const float*)d_in[2];
    float* out = (float*)d_out;

    const size_t s_s1 = (size_t)NN * TT * HH * 2;   // 65,536,000
    const size_t s_Xb = (size_t)NN * TT * II * 2;   // 16,384,000
    const size_t s_W  = (size_t)HH * II * 2;        //    524,288 (x2)
    const size_t s_W2 = (size_t)32 * HH * 2;        //     65,536 (x2)
    // + y2 4,096,000 => ~87 MB total

    char* w = (char*)d_ws;
    f16*   s1b = (f16*)w;  w += s_s1;
    f16*   Xb  = (f16*)w;  w += s_Xb;
    f16*   W1h = (f16*)w;  w += s_W;
    f16*   W1l = (f16*)w;  w += s_W;
    f16*   W2h = (f16*)w;  w += s_W2;
    f16*   W2l = (f16*)w;  w += s_W2;
    float* y2  = (float*)w;

    prep_x<<<dim3(8, 4, NN), 256, 0, stream>>>(X, Xb);
    prep_w1<<<(HH * II) / 256, 256, 0, stream>>>(W1, W1h, W1l);
    prep_w2<<<(32 * HH) / 256, 256, 0, stream>>>(W2, W2h, W2l);

    gemm1_scan1<<<dim3(8, NN), 256, 0, stream>>>(Xb, W1h, W1l, s1b);

    gemm2_mfma<<<(NN * TT) / 128, 256, 0, stream>>>(s1b, W2h, W2l, y2);
    scan2_k<<<NN, 256, 0, stream>>>(y2, out);
}